// Round 6
// baseline (125.126 us; speedup 1.0000x reference)
//
#include <hip/hip_runtime.h>
#include <hip/hip_bf16.h>

typedef float f32x4 __attribute__((ext_vector_type(4)));
typedef short s16x8 __attribute__((ext_vector_type(8)));
typedef __bf16 bf16x8 __attribute__((ext_vector_type(8)));
typedef unsigned short u16;

#define NSEQ 1024
#define EDIM 256

#define WAITVM(N) asm volatile("s_waitcnt vmcnt(" #N ")" ::: "memory")

// ---- bf16 round-to-nearest-even cast ----
__device__ __forceinline__ u16 f2bf(float f){
  union { float f; unsigned u; } v; v.f = f;
  unsigned r = v.u + 0x7FFF + ((v.u >> 16) & 1);
  return (u16)(r >> 16);
}
__device__ __forceinline__ float bf2f(u16 b){
  union { float f; unsigned u; } v; v.u = ((unsigned)b) << 16;
  return v.f;
}

// ---- MFMA wrapper with SFINAE hedge on builtin operand type (v8i16 vs v8bf16) ----
template <typename V>
__device__ __forceinline__ auto mfma_impl(V a, V b, f32x4 c, int)
    -> decltype(__builtin_amdgcn_mfma_f32_16x16x32_bf16(a, b, c, 0, 0, 0)) {
  return __builtin_amdgcn_mfma_f32_16x16x32_bf16(a, b, c, 0, 0, 0);
}
template <typename V>
__device__ __forceinline__ f32x4 mfma_impl(V a, V b, f32x4 c, long){
  bf16x8 ab = __builtin_bit_cast(bf16x8, a);
  bf16x8 bb = __builtin_bit_cast(bf16x8, b);
  return __builtin_amdgcn_mfma_f32_16x16x32_bf16(ab, bb, c, 0, 0, 0);
}
__device__ __forceinline__ f32x4 mfma16(s16x8 a, s16x8 b, f32x4 c){
  return mfma_impl(a, b, c, 0);
}

__device__ __forceinline__ void gload_lds16(const u16* g, u16* l){
  __builtin_amdgcn_global_load_lds((const __attribute__((address_space(1))) void*)g,
                                   (__attribute__((address_space(3))) void*)l, 16, 0, 0);
}

// ---- K0: cast W_v, W_o to bf16 fragment layout; extract w_q column ----
// frag layout per W: [c 8][ks 8][nt 2][lane 64][j 8], element = W[ks*32+8*(l>>4)+j][c*32+nt*16+(l&15)]
__global__ void k0_prep(const float* __restrict__ Wqkv, const float* __restrict__ Wo,
                        u16* __restrict__ wvf, u16* __restrict__ wof, float* __restrict__ wqc){
  int t = blockIdx.x * 256 + threadIdx.x;
  if (t < 16384){
    int which = t >> 13;
    int slot  = t & 8191;
    int l  = slot & 63;
    int nt = (slot >> 6) & 1;
    int ks = (slot >> 7) & 7;
    int c  = (slot >> 10) & 7;
    int row = ks*32 + 8*(l>>4);
    int col = c*32 + nt*16 + (l&15);
    s16x8 o8;
    if (which == 0){
      for (int j=0;j<8;j++) o8[j] = (short)f2bf(Wqkv[(size_t)(row+j)*513 + 257 + col]);
      *(s16x8*)(wvf + (size_t)slot*8) = o8;
    } else {
      for (int j=0;j<8;j++) o8[j] = (short)f2bf(Wo[(size_t)(row+j)*256 + col]);
      *(s16x8*)(wof + (size_t)slot*8) = o8;
    }
  } else if (t < 16384 + 256){
    int d = t - 16384;
    wqc[d] = Wqkv[(size_t)d*513];    // W_qkv[:,0] contiguous copy
  }
}

// ---- K1: per 16-row tile: q = x.wq + b0 ; x -> bf16 A-frag layout ----
// x_frag: [bp 128][rt16 64][ks 8][lane 64][j 8], elem = x[rt16*16+(l&15)][ks*32+8*(l>>4)+j]
__global__ void k1_qfrag(const float* __restrict__ x, const float* __restrict__ wqc,
                         const float* __restrict__ bqkv, u16* __restrict__ xf, float* __restrict__ q){
  int bp = blockIdx.x >> 6, rt = blockIdx.x & 63;
  const float* xt = x + ((size_t)bp*NSEQ + rt*16) * EDIM;
  __shared__ float xl[16][260];     // +4 pad: breaks bank aliasing on strided row reads
  int tid = threadIdx.x;
  for (int i=0;i<4;i++){
    int idx = tid + i*256;
    float4 vv = ((const float4*)xt)[idx];
    int row = idx >> 6, c4 = idx & 63;
    *(float4*)&xl[row][c4*4] = vv;
  }
  __syncthreads();
  int l = tid & 63, w = tid >> 6;
  int lo = l & 15, hi = l >> 4;
  for (int kk=0;kk<2;kk++){
    int ks = w*2 + kk;
    int k0 = ks*32 + 8*hi;
    s16x8 o8;
    for (int j=0;j<8;j++) o8[j] = (short)f2bf(xl[lo][k0+j]);
    size_t fo = ((((size_t)bp*64 + rt)*8 + ks)*64 + l) * 8;
    *(s16x8*)(xf + fo) = o8;
  }
  // q rows: wave w handles rows 4w..4w+3, 64-lane dot over 256 cols
  int c = l*4;
  float4 wv4 = *(const float4*)(wqc + c);
  float b0 = bqkv[0];
  for (int r=0;r<4;r++){
    int row = w*4 + r;
    float4 xv = *(float4*)&xl[row][c];
    float p = xv.x*wv4.x + xv.y*wv4.y + xv.z*wv4.z + xv.w*wv4.w;
    for (int o=32;o;o>>=1) p += __shfl_down(p, o);
    if (l == 0) q[(size_t)bp*NSEQ + rt*16 + row] = p + b0;
  }
}

// ---- K234: per bp: softmax(q) -> t = s.x (from xf frags) -> cv = t.W_k + b_k ----
// 128 blocks x 512 threads (8 waves). Wave w owns ks=w for the t-reduction.
__global__ __launch_bounds__(512) void k234(
    const u16* __restrict__ xf, const float* __restrict__ q,
    const float* __restrict__ Wqkv, const float* __restrict__ bqkv,
    float* __restrict__ cv){
  int bp = blockIdx.x;
  int tid = threadIdx.x, l = tid & 63, w = tid >> 6;
  int lo = l & 15, hi = l >> 4;
  __shared__ float sm[1024];
  __shared__ float red[16];
  __shared__ float tl[256];
  __shared__ float cvp[2][256];

  // softmax over q[bp][:]
  float2 v = ((const float2*)(q + (size_t)bp*NSEQ))[tid];
  float m = fmaxf(v.x, v.y);
  for (int o=32;o;o>>=1) m = fmaxf(m, __shfl_xor(m, o));
  if (l == 0) red[w] = m;
  __syncthreads();
  m = red[0];
#pragma unroll
  for (int i=1;i<8;i++) m = fmaxf(m, red[i]);
  float e0 = expf(v.x - m), e1 = expf(v.y - m);
  float ss = e0 + e1;
  for (int o=32;o;o>>=1) ss += __shfl_xor(ss, o);
  if (l == 0) red[8 + w] = ss;
  __syncthreads();
  float tot = red[8];
#pragma unroll
  for (int i=1;i<8;i++) tot += red[8 + i];
  float inv = 1.0f / tot;
  sm[2*tid]   = e0 * inv;
  sm[2*tid+1] = e1 * inv;
  __syncthreads();

  // t accumulation: wave w handles ks=w, all 64 rt tiles
  float acc[8];
#pragma unroll
  for (int j=0;j<8;j++) acc[j] = 0.f;
  const u16* base = xf + (((size_t)bp*64)*8 + w)*512 + (size_t)l*8;
  for (int rt=0; rt<64; rt++){
    s16x8 d8 = *(const s16x8*)(base + (size_t)rt*4096);
    float sv = sm[rt*16 + lo];
#pragma unroll
    for (int j=0;j<8;j++) acc[j] += sv * bf2f((u16)d8[j]);
  }
#pragma unroll
  for (int j=0;j<8;j++)
    for (int mm=1;mm<16;mm<<=1) acc[j] += __shfl_xor(acc[j], mm);
  if (lo == 0){
#pragma unroll
    for (int j=0;j<8;j++) tl[w*32 + 8*hi + j] = acc[j];
  }
  __syncthreads();

  // cv = b_k + t . W_k   (threads split the d-range in halves)
  int e = tid & 255, half = tid >> 8;
  float a = 0.f;
  for (int d = half*128; d < half*128 + 128; d++)
    a += tl[d] * Wqkv[(size_t)d*513 + 1 + e];
  cvp[half][e] = a;
  __syncthreads();
  if (tid < 256)
    cv[(size_t)bp*EDIM + tid] = bqkv[1 + tid] + cvp[0][tid] + cvp[1][tid];
}

// ---- K5: out = (relu(x@Wv + bv) * cv) @ Wo + bo ----
// 4 waves x 32 rows = 128 rows/block; 1024 blocks. 8 chunks of 64 cols
// (4 Wv + 4 Wo), 2x32KB double buffer, stage-at-top depth-1 prefetch,
// counted vmcnt (A: 0, B: 32 -- stores never drained), raw s_barrier.
__global__ __launch_bounds__(256, 2) void k5_main(
    const u16* __restrict__ xf, const u16* __restrict__ wvf, const u16* __restrict__ wof,
    const float* __restrict__ bqkv, const float* __restrict__ bo,
    const float* __restrict__ cv, float* __restrict__ out){
  int bp = blockIdx.x >> 3, rt = blockIdx.x & 7;
  int tid = threadIdx.x, l = tid & 63, w = tid >> 6;
  int lo = l & 15, hi = l >> 4;
  __shared__ u16 WBUF[2][16384];     // 2 x 32KB: one 64-col W chunk (full K)
  __shared__ u16 HB[4][2][16][40];   // per-wave, per-rowset h transpose slices

  // stage 64-col W chunk (0..3 = Wv, 4..7 = Wo): 8 gload_lds16 per wave
  auto stage = [&](int chunk, int buf){
    const u16* base = (chunk < 4) ? (wvf + (size_t)chunk*16384)
                                  : (wof + (size_t)(chunk-4)*16384);
    const u16* gsrc = base + (size_t)(w*8)*512 + l*8;
    u16* dst = &WBUF[buf][(size_t)(w*8)*512];
#pragma unroll
    for (int i=0;i<8;i++) gload_lds16(gsrc + i*512, dst + i*512);
  };

  stage(0, 0);

  // A-frags for 2 rowsets (16-row tiles 2w, 2w+1 of this 128-row block)
  s16x8 af0[8], af1[8];
  {
    const u16* src0 = xf + ((((size_t)bp*64 + rt*8 + 2*w + 0)*8)*64 + l)*8;
    const u16* src1 = src0 + 4096;
#pragma unroll
    for (int ks=0;ks<8;ks++){
      af0[ks] = *(const s16x8*)(src0 + (size_t)ks*512);
      af1[ks] = *(const s16x8*)(src1 + (size_t)ks*512);
    }
  }
  const float* cvb = cv + (size_t)bp*EDIM;
  // preload output bias (keeps phase-B counted-vmcnt region free of VMEM loads)
  float bov[4][4];
#pragma unroll
  for (int cc=0;cc<4;cc++)
#pragma unroll
    for (int qq=0;qq<4;qq++)
      bov[cc][qq] = bo[cc*64 + (qq>>1)*32 + (qq&1)*16 + lo];

  float* ob0 = out + ((size_t)bp*NSEQ + (rt*8 + 2*w + 0)*16) * EDIM;
  float* ob1 = ob0 + 16*EDIM;

  WAITVM(0);                       // chunk 0 staged (also drains af/bov loads)
  __builtin_amdgcn_s_barrier();
  __builtin_amdgcn_sched_barrier(0);

  s16x8 hf0[8], hf1[8];

#pragma unroll
  for (int c=0;c<8;c++){
    const int buf = c & 1;
    if (c < 7) stage(c+1, buf^1);   // depth-1 prefetch into the other buffer

    f32x4 acc0[4], acc1[4];
#pragma unroll
    for (int q=0;q<4;q++){
      acc0[q] = f32x4{0.f,0.f,0.f,0.f};
      acc1[q] = f32x4{0.f,0.f,0.f,0.f};
    }

    __builtin_amdgcn_s_setprio(1);
#pragma unroll
    for (int ks=0;ks<8;ks++){
      s16x8 b[4];
#pragma unroll
      for (int q=0;q<4;q++)   // q = s*2+nt: sub-32col s = q>>1, nt = q&1
        b[q] = *(const s16x8*)&WBUF[buf][(size_t)(q>>1)*8192 + (size_t)(ks*2+(q&1))*512 + l*8];
#pragma unroll
      for (int q=0;q<4;q++){
        if (c < 4){
          acc0[q] = mfma16(af0[ks], b[q], acc0[q]);
          acc1[q] = mfma16(af1[ks], b[q], acc1[q]);
        } else {
          acc0[q] = mfma16(hf0[ks], b[q], acc0[q]);
          acc1[q] = mfma16(hf1[ks], b[q], acc1[q]);
        }
      }
    }
    __builtin_amdgcn_s_setprio(0);

    if (c < 4){
      // epilogue A: h = relu(acc+bv)*cv -> HB scatter -> hf A-frags (wave-private)
#pragma unroll
      for (int s=0;s<2;s++){
        int colA = c*64 + s*32 + lo, colB = colA + 16;
        float bvA = bqkv[257 + colA], bvB = bqkv[257 + colB];
        float csA = cvb[colA],        csB = cvb[colB];
#pragma unroll
        for (int r=0;r<4;r++){
          float h00 = acc0[s*2][r]   + bvA, h01 = acc0[s*2+1][r] + bvB;
          float h10 = acc1[s*2][r]   + bvA, h11 = acc1[s*2+1][r] + bvB;
          HB[w][0][hi*4 + r][lo]      = f2bf(h00 > 0.f ? h00*csA : 0.f);
          HB[w][0][hi*4 + r][16 + lo] = f2bf(h01 > 0.f ? h01*csB : 0.f);
          HB[w][1][hi*4 + r][lo]      = f2bf(h10 > 0.f ? h10*csA : 0.f);
          HB[w][1][hi*4 + r][16 + lo] = f2bf(h11 > 0.f ? h11*csB : 0.f);
        }
        hf0[2*c + s] = *(const s16x8*)&HB[w][0][lo][8*hi];
        hf1[2*c + s] = *(const s16x8*)&HB[w][1][lo][8*hi];
      }
    } else {
      // epilogue B: out stores (retired lazily; never drained mid-loop)
      int c2 = c - 4;
#pragma unroll
      for (int s=0;s<2;s++){
        int colA = c2*64 + s*32 + lo;
#pragma unroll
        for (int r=0;r<4;r++){
          size_t ro = (size_t)(hi*4 + r)*EDIM;
          ob0[ro + colA]      = acc0[s*2][r]   + bov[c2][s*2];
          ob0[ro + colA + 16] = acc0[s*2+1][r] + bov[c2][s*2+1];
          ob1[ro + colA]      = acc1[s*2][r]   + bov[c2][s*2];
          ob1[ro + colA + 16] = acc1[s*2+1][r] + bov[c2][s*2+1];
        }
      }
    }

    // counted wait: chunk c+1 must be staged before next iter.
    // A iters: queue = [bias/cv loads][stage 8] -> vmcnt(0) (all cheap, L2-hot).
    // B iters: queue = [old stores][stage 8][new stores 32] -> vmcnt(32)
    //          retires old stores + stage exactly, leaves this iter's stores.
    if (c < 7){
      if (c < 4) WAITVM(0); else WAITVM(32);
      __builtin_amdgcn_s_barrier();
      __builtin_amdgcn_sched_barrier(0);
    }
  }
}

extern "C" void kernel_launch(void* const* d_in, const int* in_sizes, int n_in,
                              void* d_out, int out_size, void* d_ws, size_t ws_size,
                              hipStream_t stream){
  const float* x    = (const float*)d_in[0];
  const float* Wqkv = (const float*)d_in[1];
  const float* bqkv = (const float*)d_in[2];
  const float* Wo   = (const float*)d_in[3];
  const float* bo   = (const float*)d_in[4];
  float* out = (float*)d_out;
  char* ws = (char*)d_ws;
  u16*   xf  = (u16*)(ws);                       // 67108864 B
  u16*   wvf = (u16*)(ws + 67108864);            //   131072 B
  u16*   wof = (u16*)(ws + 67239936);            //   131072 B (adjacent to wvf)
  float* q   = (float*)(ws + 67371008);          //   524288 B
  float* cvv = (float*)(ws + 69468160);          //   131072 B
  float* wqc = (float*)(ws + 69599232);          //     1024 B

  hipLaunchKernelGGL(k0_prep,    dim3(65),   dim3(256), 0, stream, Wqkv, Wo, wvf, wof, wqc);
  hipLaunchKernelGGL(k1_qfrag,   dim3(8192), dim3(256), 0, stream, x, wqc, bqkv, xf, q);
  hipLaunchKernelGGL(k234,       dim3(128),  dim3(512), 0, stream, xf, q, Wqkv, bqkv, cvv);
  hipLaunchKernelGGL(k5_main,    dim3(1024), dim3(256), 0, stream, xf, wvf, wof, bqkv, bo, cvv, out);
}

// Round 7
// 118.976 us; speedup vs baseline: 1.0517x; 1.0517x over previous
//
#include <hip/hip_runtime.h>
#include <hip/hip_bf16.h>

typedef float f32x4 __attribute__((ext_vector_type(4)));
typedef short s16x8 __attribute__((ext_vector_type(8)));
typedef __bf16 bf16x8 __attribute__((ext_vector_type(8)));
typedef unsigned short u16;

#define NSEQ 1024
#define EDIM 256

#define WAITVM(N) asm volatile("s_waitcnt vmcnt(" #N ")" ::: "memory")

// ---- bf16 round-to-nearest-even cast ----
__device__ __forceinline__ u16 f2bf(float f){
  union { float f; unsigned u; } v; v.f = f;
  unsigned r = v.u + 0x7FFF + ((v.u >> 16) & 1);
  return (u16)(r >> 16);
}
__device__ __forceinline__ float bf2f(u16 b){
  union { float f; unsigned u; } v; v.u = ((unsigned)b) << 16;
  return v.f;
}

// ---- MFMA wrapper with SFINAE hedge on builtin operand type (v8i16 vs v8bf16) ----
template <typename V>
__device__ __forceinline__ auto mfma_impl(V a, V b, f32x4 c, int)
    -> decltype(__builtin_amdgcn_mfma_f32_16x16x32_bf16(a, b, c, 0, 0, 0)) {
  return __builtin_amdgcn_mfma_f32_16x16x32_bf16(a, b, c, 0, 0, 0);
}
template <typename V>
__device__ __forceinline__ f32x4 mfma_impl(V a, V b, f32x4 c, long){
  bf16x8 ab = __builtin_bit_cast(bf16x8, a);
  bf16x8 bb = __builtin_bit_cast(bf16x8, b);
  return __builtin_amdgcn_mfma_f32_16x16x32_bf16(ab, bb, c, 0, 0, 0);
}
__device__ __forceinline__ f32x4 mfma16(s16x8 a, s16x8 b, f32x4 c){
  return mfma_impl(a, b, c, 0);
}

__device__ __forceinline__ void gload_lds16(const u16* g, u16* l){
  __builtin_amdgcn_global_load_lds((const __attribute__((address_space(1))) void*)g,
                                   (__attribute__((address_space(3))) void*)l, 16, 0, 0);
}

// ---- K0: cast W_v, W_o to bf16 fragment layout; extract w_q column ----
// frag layout per W: [c 8][ks 8][nt 2][lane 64][j 8], element = W[ks*32+8*(l>>4)+j][c*32+nt*16+(l&15)]
__global__ void k0_prep(const float* __restrict__ Wqkv, const float* __restrict__ Wo,
                        u16* __restrict__ wvf, u16* __restrict__ wof, float* __restrict__ wqc){
  int t = blockIdx.x * 256 + threadIdx.x;
  if (t < 16384){
    int which = t >> 13;
    int slot  = t & 8191;
    int l  = slot & 63;
    int nt = (slot >> 6) & 1;
    int ks = (slot >> 7) & 7;
    int c  = (slot >> 10) & 7;
    int row = ks*32 + 8*(l>>4);
    int col = c*32 + nt*16 + (l&15);
    s16x8 o8;
    if (which == 0){
      for (int j=0;j<8;j++) o8[j] = (short)f2bf(Wqkv[(size_t)(row+j)*513 + 257 + col]);
      *(s16x8*)(wvf + (size_t)slot*8) = o8;
    } else {
      for (int j=0;j<8;j++) o8[j] = (short)f2bf(Wo[(size_t)(row+j)*256 + col]);
      *(s16x8*)(wof + (size_t)slot*8) = o8;
    }
  } else if (t < 16384 + 256){
    int d = t - 16384;
    wqc[d] = Wqkv[(size_t)d*513];    // W_qkv[:,0] contiguous copy
  }
}

// ---- K1: per 16-row tile: x -> bf16 A-frag layout ; q = x.wq + b0 ;
//      online-softmax partials: m_b, z_b, u_b = sum_r e^{q_r - m_b} * x_r ----
// x_frag: [bp 128][rt16 64][ks 8][lane 64][j 8], elem = x[rt16*16+(l&15)][ks*32+8*(l>>4)+j]
__global__ void k1_qfrag(const float* __restrict__ x, const float* __restrict__ wqc,
                         const float* __restrict__ bqkv, u16* __restrict__ xf,
                         float* __restrict__ pm, float* __restrict__ pu){
  int bp = blockIdx.x >> 6, rt = blockIdx.x & 63;
  const float* xt = x + ((size_t)bp*NSEQ + rt*16) * EDIM;
  __shared__ float xl[16][260];     // +4 pad: breaks bank aliasing on strided row reads
  __shared__ float qs[16], es[16];
  int tid = threadIdx.x;
  for (int i=0;i<4;i++){
    int idx = tid + i*256;
    float4 vv = ((const float4*)xt)[idx];
    int row = idx >> 6, c4 = idx & 63;
    *(float4*)&xl[row][c4*4] = vv;
  }
  __syncthreads();
  int l = tid & 63, w = tid >> 6;
  int lo = l & 15, hi = l >> 4;
  for (int kk=0;kk<2;kk++){
    int ks = w*2 + kk;
    int k0 = ks*32 + 8*hi;
    s16x8 o8;
    for (int j=0;j<8;j++) o8[j] = (short)f2bf(xl[lo][k0+j]);
    size_t fo = ((((size_t)bp*64 + rt)*8 + ks)*64 + l) * 8;
    *(s16x8*)(xf + fo) = o8;
  }
  // q rows: wave w handles rows 4w..4w+3, 64-lane dot over 256 cols
  int c = l*4;
  float4 wv4 = *(const float4*)(wqc + c);
  float b0 = bqkv[0];
  for (int r=0;r<4;r++){
    int row = w*4 + r;
    float4 xv = *(float4*)&xl[row][c];
    float p = xv.x*wv4.x + xv.y*wv4.y + xv.z*wv4.z + xv.w*wv4.w;
    for (int o=32;o;o>>=1) p += __shfl_down(p, o);
    if (l == 0) qs[row] = p + b0;
  }
  __syncthreads();
  // block-local softmax partials over the 16 rows
  float mb = qs[0];
#pragma unroll
  for (int i=1;i<16;i++) mb = fmaxf(mb, qs[i]);
  if (tid < 16) es[tid] = expf(qs[tid] - mb);
  __syncthreads();
  float u = 0.f;
#pragma unroll
  for (int r=0;r<16;r++) u += es[r] * xl[r][tid];
  pu[(((size_t)bp*64 + rt))*256 + tid] = u;
  if (tid == 0){
    float zb = 0.f;
#pragma unroll
    for (int r=0;r<16;r++) zb += es[r];
    pm[((size_t)bp*64 + rt)*2 + 0] = mb;
    pm[((size_t)bp*64 + rt)*2 + 1] = zb;
  }
}

// ---- K34: per bp: combine 64 partials -> t ; cv = t.W_k + b_k ----
// 128 blocks x 512 threads.
__global__ __launch_bounds__(512) void k34(
    const float* __restrict__ pm, const float* __restrict__ pu,
    const float* __restrict__ Wqkv, const float* __restrict__ bqkv,
    float* __restrict__ cv){
  int bp = blockIdx.x, tid = threadIdx.x;
  __shared__ float mzl[128];     // interleaved (m_b, z_b)
  __shared__ float sf[64];
  __shared__ float tp2[2][256];
  __shared__ float tl[256];
  __shared__ float cvp[2][256];
  if (tid < 128) mzl[tid] = pm[(size_t)bp*128 + tid];
  __syncthreads();
  float M = mzl[0];
#pragma unroll
  for (int b=1;b<64;b++) M = fmaxf(M, mzl[2*b]);
  if (tid < 64) sf[tid] = expf(mzl[2*tid] - M);
  __syncthreads();
  float Z = 0.f;
#pragma unroll
  for (int b=0;b<64;b++) Z += mzl[2*b+1] * sf[b];
  float invZ = 1.0f / Z;
  int e = tid & 255, half = tid >> 8;
  float t = 0.f;
  for (int b = half*32; b < half*32 + 32; b++)
    t += pu[((size_t)bp*64 + b)*256 + e] * sf[b];
  tp2[half][e] = t;
  __syncthreads();
  if (tid < 256) tl[tid] = (tp2[0][tid] + tp2[1][tid]) * invZ;
  __syncthreads();
  float a = 0.f;
  for (int d = half*128; d < half*128 + 128; d++)
    a += tl[d] * Wqkv[(size_t)d*513 + 1 + e];
  cvp[half][e] = a;
  __syncthreads();
  if (tid < 256)
    cv[(size_t)bp*EDIM + tid] = bqkv[1 + tid] + cvp[0][tid] + cvp[1][tid];
}

// ---- K5: out = (relu(x@Wv + bv) * cv) @ Wo + bo ----
// 4 waves x 32 rows = 128 rows/block; 1024 blocks. 8 chunks of 64 cols
// (4 Wv + 4 Wo), 2x32KB double buffer, stage-at-top depth-1 prefetch,
// counted vmcnt (A: 0, B: 32 -- stores never drained), raw s_barrier.
// HB transpose slice shared between rowsets (two-pass; per-wave in-order LDS).
__global__ __launch_bounds__(256, 2) void k5_main(
    const u16* __restrict__ xf, const u16* __restrict__ wvf, const u16* __restrict__ wof,
    const float* __restrict__ bqkv, const float* __restrict__ bo,
    const float* __restrict__ cv, float* __restrict__ out){
  int bp = blockIdx.x >> 3, rt = blockIdx.x & 7;
  int tid = threadIdx.x, l = tid & 63, w = tid >> 6;
  int lo = l & 15, hi = l >> 4;
  __shared__ u16 WBUF[2][16384];     // 2 x 32KB: one 64-col W chunk (full K)
  __shared__ u16 HB[4][16][40];      // per-wave h transpose slice (shared by rowsets)

  // stage 64-col W chunk (0..3 = Wv, 4..7 = Wo): 8 gload_lds16 per wave
  auto stage = [&](int chunk, int buf){
    const u16* base = (chunk < 4) ? (wvf + (size_t)chunk*16384)
                                  : (wof + (size_t)(chunk-4)*16384);
    const u16* gsrc = base + (size_t)(w*8)*512 + l*8;
    u16* dst = &WBUF[buf][(size_t)(w*8)*512];
#pragma unroll
    for (int i=0;i<8;i++) gload_lds16(gsrc + i*512, dst + i*512);
  };

  stage(0, 0);

  // A-frags for 2 rowsets (16-row tiles 2w, 2w+1 of this 128-row block)
  s16x8 af0[8], af1[8];
  {
    const u16* src0 = xf + ((((size_t)bp*64 + rt*8 + 2*w + 0)*8)*64 + l)*8;
    const u16* src1 = src0 + 4096;
#pragma unroll
    for (int ks=0;ks<8;ks++){
      af0[ks] = *(const s16x8*)(src0 + (size_t)ks*512);
      af1[ks] = *(const s16x8*)(src1 + (size_t)ks*512);
    }
  }
  const float* cvb = cv + (size_t)bp*EDIM;
  // preload output bias (keeps phase-B counted-vmcnt region free of VMEM loads)
  float bov[4][4];
#pragma unroll
  for (int cc=0;cc<4;cc++)
#pragma unroll
    for (int qq=0;qq<4;qq++)
      bov[cc][qq] = bo[cc*64 + (qq>>1)*32 + (qq&1)*16 + lo];

  float* ob0 = out + ((size_t)bp*NSEQ + (rt*8 + 2*w + 0)*16) * EDIM;
  float* ob1 = ob0 + 16*EDIM;

  WAITVM(0);                       // chunk 0 staged (also drains af/bov loads)
  __builtin_amdgcn_s_barrier();
  __builtin_amdgcn_sched_barrier(0);

  s16x8 hf0[8], hf1[8];

#pragma unroll
  for (int c=0;c<8;c++){
    const int buf = c & 1;
    if (c < 7) stage(c+1, buf^1);   // depth-1 prefetch into the other buffer

    f32x4 acc0[4], acc1[4];
#pragma unroll
    for (int q=0;q<4;q++){
      acc0[q] = f32x4{0.f,0.f,0.f,0.f};
      acc1[q] = f32x4{0.f,0.f,0.f,0.f};
    }

    __builtin_amdgcn_s_setprio(1);
#pragma unroll
    for (int ks=0;ks<8;ks++){
      s16x8 b[4];
#pragma unroll
      for (int q=0;q<4;q++)   // q = s*2+nt: sub-32col s = q>>1, nt = q&1
        b[q] = *(const s16x8*)&WBUF[buf][(size_t)(q>>1)*8192 + (size_t)(ks*2+(q&1))*512 + l*8];
#pragma unroll
      for (int q=0;q<4;q++){
        if (c < 4){
          acc0[q] = mfma16(af0[ks], b[q], acc0[q]);
          acc1[q] = mfma16(af1[ks], b[q], acc1[q]);
        } else {
          acc0[q] = mfma16(hf0[ks], b[q], acc0[q]);
          acc1[q] = mfma16(hf1[ks], b[q], acc1[q]);
        }
      }
    }
    __builtin_amdgcn_s_setprio(0);

    if (c < 4){
      // epilogue A: h = relu(acc+bv)*cv -> HB -> hf A-frags, rowset-by-rowset
      // (shared HB slice: per-wave LDS ops retire in order, so the rs=1 writes
      //  cannot pass the rs=0 b128 read of the same addresses)
#pragma unroll
      for (int rs=0;rs<2;rs++){
#pragma unroll
        for (int s=0;s<2;s++){
          int colA = c*64 + s*32 + lo, colB = colA + 16;
          float bvA = bqkv[257 + colA], bvB = bqkv[257 + colB];
          float csA = cvb[colA],        csB = cvb[colB];
#pragma unroll
          for (int r=0;r<4;r++){
            float hA = (rs ? acc1[s*2][r]   : acc0[s*2][r])   + bvA;
            float hB = (rs ? acc1[s*2+1][r] : acc0[s*2+1][r]) + bvB;
            HB[w][hi*4 + r][lo]      = f2bf(hA > 0.f ? hA*csA : 0.f);
            HB[w][hi*4 + r][16 + lo] = f2bf(hB > 0.f ? hB*csB : 0.f);
          }
          if (rs == 0) hf0[2*c + s] = *(const s16x8*)&HB[w][lo][8*hi];
          else         hf1[2*c + s] = *(const s16x8*)&HB[w][lo][8*hi];
        }
      }
    } else {
      // epilogue B: out stores (retired lazily; never drained mid-loop)
      int c2 = c - 4;
#pragma unroll
      for (int s=0;s<2;s++){
        int colA = c2*64 + s*32 + lo;
#pragma unroll
        for (int r=0;r<4;r++){
          size_t ro = (size_t)(hi*4 + r)*EDIM;
          ob0[ro + colA]      = acc0[s*2][r]   + bov[c2][s*2];
          ob0[ro + colA + 16] = acc0[s*2+1][r] + bov[c2][s*2+1];
          ob1[ro + colA]      = acc1[s*2][r]   + bov[c2][s*2];
          ob1[ro + colA + 16] = acc1[s*2+1][r] + bov[c2][s*2+1];
        }
      }
    }

    // counted wait: chunk c+1 must be staged before next iter.
    // A iters: queue = [stage 8][epi loads] -> vmcnt(0) (robust even if the
    //   compiler hoists the bqkv/cv loads; stage was issued a full chunk ago).
    // B iters: queue = [old stores 32][stage 8][new stores 32] -> vmcnt(32)
    //          retires old stores + stage exactly, leaves this iter's stores.
    if (c < 7){
      if (c < 4) WAITVM(0); else WAITVM(32);
      __builtin_amdgcn_s_barrier();
      __builtin_amdgcn_sched_barrier(0);
    }
  }
}

extern "C" void kernel_launch(void* const* d_in, const int* in_sizes, int n_in,
                              void* d_out, int out_size, void* d_ws, size_t ws_size,
                              hipStream_t stream){
  const float* x    = (const float*)d_in[0];
  const float* Wqkv = (const float*)d_in[1];
  const float* bqkv = (const float*)d_in[2];
  const float* Wo   = (const float*)d_in[3];
  const float* bo   = (const float*)d_in[4];
  float* out = (float*)d_out;
  char* ws = (char*)d_ws;
  u16*   xf  = (u16*)(ws);                       // 67108864 B
  u16*   wvf = (u16*)(ws + 67108864);            //   131072 B
  u16*   wof = (u16*)(ws + 67239936);            //   131072 B (adjacent to wvf)
  float* pm  = (float*)(ws + 67371008);          //    65536 B (m_b, z_b)
  float* pu  = (float*)(ws + 67436544);          //  8388608 B (u_b partials)
  float* cvv = (float*)(ws + 75825152);          //   131072 B
  float* wqc = (float*)(ws + 75956224);          //     1024 B

  hipLaunchKernelGGL(k0_prep,  dim3(65),   dim3(256), 0, stream, Wqkv, Wo, wvf, wof, wqc);
  hipLaunchKernelGGL(k1_qfrag, dim3(8192), dim3(256), 0, stream, x, wqc, bqkv, xf, pm, pu);
  hipLaunchKernelGGL(k34,      dim3(128),  dim3(512), 0, stream, pm, pu, Wqkv, bqkv, cvv);
  hipLaunchKernelGGL(k5_main,  dim3(1024), dim3(256), 0, stream, xf, wvf, wof, bqkv, bo, cvv, out);
}